// Round 4
// baseline (117.645 us; speedup 1.0000x reference)
//
#include <hip/hip_runtime.h>
#include <math.h>

// Depthwise 5x5 Gaussian blur, sigma from device scalar.
// x: (16, 256, 64, 64) fp32, out same, zero pad 2. Separable.
//
// Barrier-free / LDS-free design: ONE WAVE PER PLANE.
// Lane (l) owns column-quad c4 = l&15 and row strip [g16, g16+16), g16=(l>>4)*16.
// 20 float4 global loads per lane (16 own rows + 4 halo rows, redundantly
// loaded), horizontal 5-tap via __shfl for the 2-col halos, vertical 5-tap
// from the register-resident h[20] window, 16 float4 stores.
// No __syncthreads anywhere -> waves free-run and self-stagger, keeping the
// memory pipe continuously busy instead of phase-locked bursts.

constexpr int Hh = 64;
constexpr int Ww = 64;
constexpr int KS = 5;
constexpr int PADc = 2;

__global__ __launch_bounds__(256, 2) void gauss5(const float* __restrict__ x,
                                                 const float* __restrict__ sigma,
                                                 float* __restrict__ out) {
    const int t    = threadIdx.x;
    const int lane = t & 63;
    const int wid  = t >> 6;                       // wave index within block
    const size_t plane = (size_t)blockIdx.x * 4 + wid;

    const int c4  = lane & 15;                     // column quad 0..15
    const int g16 = (lane >> 4) << 4;              // first output row of strip

    // --- normalized 1-D Gaussian taps (outer product sums to 1, matching ref) ---
    const float sg = sigma[0];
    const float c2 = -1.0f / (2.0f * sg * sg);
    float w[KS];
    float wsum = 0.0f;
#pragma unroll
    for (int i = 0; i < KS; ++i) {
        float d = (float)(i - PADc);
        w[i] = expf(d * d * c2);
        wsum += w[i];
    }
    const float winv = 1.0f / wsum;
#pragma unroll
    for (int i = 0; i < KS; ++i) w[i] *= winv;

    const float4* __restrict__ x4 = (const float4*)(x + plane * (Hh * Ww));
    float4* __restrict__ o4       = (float4*)(out + plane * (Hh * Ww));

    const int lm1 = lane - 1;                      // shfl sources (cross-group
    const int lp1 = lane + 1;                      //  cases are masked below)
    const bool leftEdge  = (c4 == 0);
    const bool rightEdge = (c4 == 15);

    // --- load 20 rows (2 top halo + 16 own + 2 bottom halo), horizontal conv ---
    float4 h[20];
#pragma unroll
    for (int i = 0; i < 20; ++i) {
        int ri = g16 - PADc + i;                   // input row (may be OOB)
        int rc = ri < 0 ? 0 : (ri > 63 ? 63 : ri); // clamped (safe) address
        float4 v = x4[rc * 16 + c4];
        if (ri != rc) { v.x = 0.f; v.y = 0.f; v.z = 0.f; v.w = 0.f; }  // zero pad

        // 2-col halos from neighbor lanes (all lanes in a 16-lane row group
        // share ri, so halo zeroing above is consistent across the shfl).
        float lz = __shfl(v.z, lm1, 64);
        float lw = __shfl(v.w, lm1, 64);
        float rx = __shfl(v.x, lp1, 64);
        float ry = __shfl(v.y, lp1, 64);
        lz = leftEdge  ? 0.f : lz;
        lw = leftEdge  ? 0.f : lw;
        rx = rightEdge ? 0.f : rx;
        ry = rightEdge ? 0.f : ry;

        h[i].x = w[0]*lz  + w[1]*lw  + w[2]*v.x + w[3]*v.y + w[4]*v.z;
        h[i].y = w[0]*lw  + w[1]*v.x + w[2]*v.y + w[3]*v.z + w[4]*v.w;
        h[i].z = w[0]*v.x + w[1]*v.y + w[2]*v.z + w[3]*v.w + w[4]*rx;
        h[i].w = w[0]*v.y + w[1]*v.z + w[2]*v.w + w[3]*rx  + w[4]*ry;
    }

    // --- vertical conv + store ---
#pragma unroll
    for (int r = 0; r < 16; ++r) {
        float4 a;
        a.x = w[0]*h[r].x; a.y = w[0]*h[r].y; a.z = w[0]*h[r].z; a.w = w[0]*h[r].w;
#pragma unroll
        for (int j = 1; j < KS; ++j) {
            a.x += w[j] * h[r + j].x;
            a.y += w[j] * h[r + j].y;
            a.z += w[j] * h[r + j].z;
            a.w += w[j] * h[r + j].w;
        }
        o4[(g16 + r) * 16 + c4] = a;
    }
}

extern "C" void kernel_launch(void* const* d_in, const int* in_sizes, int n_in,
                              void* d_out, int out_size, void* d_ws, size_t ws_size,
                              hipStream_t stream) {
    const float* x     = (const float*)d_in[0];
    const float* sigma = (const float*)d_in[1];
    float* out         = (float*)d_out;
    const int planes = in_sizes[0] / (Hh * Ww);  // 4096
    gauss5<<<planes / 4, 256, 0, stream>>>(x, sigma, out);  // 1 wave : 1 plane
}